// Round 5
// baseline (2259.852 us; speedup 1.0000x reference)
//
#include <hip/hip_runtime.h>
#include <math.h>

#define NPATCH 100000
#define CDIM   256
#define NMOOD  64
#define NGENRE 256
#define NSUB   512
#define NLBL   832          // 64+256+512
#define KTOP   9

// ---- f32 fallback screen constants (R4, known-green) ----
#define NCHUNK 39
#define CHUNK  2624
#define BLK    64
#define KC     32
#define KP     12

// ---- MFMA screen constants ----
#define PBLK   1600         // patches per chunk
#define NCH3   63           // 63*1600 = 100800 >= 100000
#define KPS    16           // per-(label,chunk) partial size
#define SL     6            // per-lane list depth
#define NCAND  32           // exact re-rank candidate count

typedef __attribute__((ext_vector_type(8))) short bf16x8;
typedef __attribute__((ext_vector_type(8))) unsigned short u16x8;
typedef __attribute__((ext_vector_type(4))) float f32x4;

// ---------------- serial top-k insert (ascending by (val,idx)) --------------

template <int K>
__device__ __forceinline__ void tk_insert(float (&v)[K], int (&ii)[K],
                                          float s, int idx) {
  if (s < v[K - 1] || (s == v[K - 1] && idx < ii[K - 1])) {
    v[K - 1] = s; ii[K - 1] = idx;
#pragma unroll
    for (int t = K - 1; t > 0; --t) {
      bool sw = (v[t] < v[t - 1]) || (v[t] == v[t - 1] && ii[t] < ii[t - 1]);
      if (sw) {
        float fv = v[t]; v[t] = v[t - 1]; v[t - 1] = fv;
        int fi = ii[t]; ii[t] = ii[t - 1]; ii[t - 1] = fi;
      }
    }
  }
}

// ------ numpy-pairwise sum of squares over 256 contiguous floats ------------

__device__ float np_sq256(const float* a) {
  float b0, b1;
  {
    float r[8];
#pragma unroll
    for (int i = 0; i < 8; ++i) { float x = a[i]; r[i] = __fmul_rn(x, x); }
    for (int j = 8; j < 128; j += 8)
#pragma unroll
      for (int i = 0; i < 8; ++i) {
        float x = a[j + i];
        r[i] = __fadd_rn(r[i], __fmul_rn(x, x));
      }
    b0 = __fadd_rn(__fadd_rn(__fadd_rn(r[0], r[1]), __fadd_rn(r[2], r[3])),
                   __fadd_rn(__fadd_rn(r[4], r[5]), __fadd_rn(r[6], r[7])));
  }
  {
    float r[8];
#pragma unroll
    for (int i = 0; i < 8; ++i) { float x = a[128 + i]; r[i] = __fmul_rn(x, x); }
    for (int j = 8; j < 128; j += 8)
#pragma unroll
      for (int i = 0; i < 8; ++i) {
        float x = a[128 + j + i];
        r[i] = __fadd_rn(r[i], __fmul_rn(x, x));
      }
    b1 = __fadd_rn(__fadd_rn(__fadd_rn(r[0], r[1]), __fadd_rn(r[2], r[3])),
                   __fadd_rn(__fadd_rn(r[4], r[5]), __fadd_rn(r[6], r[7])));
  }
  return __fadd_rn(b0, b1);
}

__device__ __forceinline__ float np_key(float ln, float dot, float pn) {
  return __fadd_rn(__fsub_rn(ln, __fmul_rn(2.f, dot)), pn);
}

// ---------------- kernel: concat labels into one (832,256) matrix -----------

__global__ void k_concat_labels(const float* __restrict__ mood,
                                const float* __restrict__ genre,
                                const float* __restrict__ sub,
                                float* __restrict__ lbl) {
  int i = blockIdx.x * 256 + threadIdx.x;
  if (i < NMOOD * CDIM) lbl[i] = mood[i];
  else if (i < (NMOOD + NGENRE) * CDIM) lbl[i] = genre[i - NMOOD * CDIM];
  else lbl[i] = sub[i - (NMOOD + NGENRE) * CDIM];
}

// ---------------- kernel: wave-parallel numpy-pairwise row norms ------------
// 8 rows x 8 accumulators per wave; bit-identical to np_sq256 (commutative
// swaps only in the combine tree). Requires n % 8 == 0.

__global__ void k_norms_wave(const float* __restrict__ m, int n,
                             float* __restrict__ out) {
  int gw = (blockIdx.x * blockDim.x + threadIdx.x) >> 6;
  int lane = threadIdx.x & 63;
  int rsub = lane >> 3, i = lane & 7;
  int nw = (gridDim.x * blockDim.x) >> 6;
  for (int row0 = gw * 8; row0 < n; row0 += nw * 8) {
    int row = row0 + rsub;
    const float* a = m + (size_t)row * CDIM;
    float b[2];
#pragma unroll
    for (int blk = 0; blk < 2; ++blk) {
      const float* ab = a + blk * 128;
      float x = ab[i];
      float r = __fmul_rn(x, x);
      for (int j = 1; j < 16; ++j) {
        float y = ab[j * 8 + i];
        r = __fadd_rn(r, __fmul_rn(y, y));
      }
      float t = __fadd_rn(r, __shfl_xor(r, 1));
      t = __fadd_rn(t, __shfl_xor(t, 2));
      t = __fadd_rn(t, __shfl_xor(t, 4));
      b[blk] = t;
    }
    if (i == 0) out[row] = __fadd_rn(b[0], b[1]);
  }
}

// ---------------- kernel: f32 -> bf16 (RNE) conversion ----------------------

__device__ __forceinline__ unsigned short f2bf(float x) {
  unsigned u = __float_as_uint(x);
  return (unsigned short)((u + 0x7fffu + ((u >> 16) & 1u)) >> 16);
}

__global__ void k_tobf16(const float* __restrict__ src, size_t n8,
                         unsigned short* __restrict__ dst) {
  size_t i = (size_t)blockIdx.x * blockDim.x + threadIdx.x;
  size_t stride = (size_t)gridDim.x * blockDim.x;
  for (; i < n8; i += stride) {
    const float4* s = (const float4*)(src + i * 8);
    float4 x = s[0], y = s[1];
    u16x8 o;
    o[0] = f2bf(x.x); o[1] = f2bf(x.y); o[2] = f2bf(x.z); o[3] = f2bf(x.w);
    o[4] = f2bf(y.x); o[5] = f2bf(y.y); o[6] = f2bf(y.z); o[7] = f2bf(y.w);
    *(u16x8*)(dst + i * 8) = o;
  }
}

// ---------------- kernel: MFMA bf16 screen ----------------------------------
// grid (13 label-groups, 63 chunks); block 256 = 4 waves, wave owns 16 labels.
// No barriers in the main loop; per-lane register top-lists; one block-end
// merge to per-(label,chunk) top-16 partials. Keys are APPROXIMATE (bf16):
// selection is finalized by exact f32 re-rank in k_merge_mfma.

__global__ __launch_bounds__(256) void k_screen_mfma(
    const unsigned short* __restrict__ lblbf,
    const unsigned short* __restrict__ patchbf,
    const float* __restrict__ pnorm,
    float* __restrict__ part_s, int* __restrict__ part_i) {
  __shared__ float stv[64][16][SL];
  __shared__ int   sti[64][16][SL];
  const int tid = threadIdx.x;
  const int w = tid >> 6, l = tid & 63;
  const int col = l & 15, kg = l >> 4;
  const int lgrp = blockIdx.x;
  const int chunk = blockIdx.y;
  const int lab0 = lgrp * 64 + w * 16;
  const int p0 = chunk * PBLK;

  bf16x8 a[8];
#pragma unroll
  for (int kk = 0; kk < 8; ++kk)
    a[kk] = *(const bf16x8*)&lblbf[(size_t)(lab0 + col) * CDIM + kk * 32 + kg * 8];

  float lv[4][SL]; int li[4][SL];
#pragma unroll
  for (int r = 0; r < 4; ++r)
#pragma unroll
    for (int j = 0; j < SL; ++j) { lv[r][j] = INFINITY; li[r][j] = 0x7fffffff; }

  for (int g = 0; g < PBLK / 16; ++g) {
    int p = p0 + g * 16 + col;
    int pc = p < NPATCH ? p : NPATCH - 1;
    const unsigned short* prow = &patchbf[(size_t)pc * CDIM + kg * 8];
    bf16x8 b[8];
#pragma unroll
    for (int kk = 0; kk < 8; ++kk) b[kk] = *(const bf16x8*)&prow[kk * 32];
    f32x4 acc = {0.f, 0.f, 0.f, 0.f};
#pragma unroll
    for (int kk = 0; kk < 8; ++kk)
      acc = __builtin_amdgcn_mfma_f32_16x16x32_bf16(a[kk], b[kk], acc, 0, 0, 0);
    bool ok = p < NPATCH;
    float pn = pnorm[pc];
    int pi = ok ? p : 0x7fffffff;
#pragma unroll
    for (int r = 0; r < 4; ++r) {
      float key = ok ? fmaf(-2.f, acc[r], pn) : INFINITY;
      tk_insert<SL>(lv[r], li[r], key, pi);
    }
  }

#pragma unroll
  for (int r = 0; r < 4; ++r) {
    int s = w * 16 + kg * 4 + r;
#pragma unroll
    for (int j = 0; j < SL; ++j) { stv[s][col][j] = lv[r][j]; sti[s][col][j] = li[r][j]; }
  }
  __syncthreads();
  if (tid < 64) {
    float v[KPS]; int ii[KPS];
#pragma unroll
    for (int j = 0; j < KPS; ++j) { v[j] = INFINITY; ii[j] = 0x7fffffff; }
    for (int src = 0; src < 16; ++src)
#pragma unroll
      for (int j = 0; j < SL; ++j)
        tk_insert<KPS>(v, ii, stv[tid][src][j], sti[tid][src][j]);
    size_t base = ((size_t)(lgrp * 64 + tid) * NCH3 + chunk) * KPS;
#pragma unroll
    for (int j = 0; j < KPS; ++j) { part_s[base + j] = v[j]; part_i[base + j] = ii[j]; }
  }
}

// ---------------- kernel: merge + EXACT np-f32 re-rank + max-agg ------------

__global__ void k_merge_mfma(const float* __restrict__ part_s,
                             const int* __restrict__ part_i,
                             const float* __restrict__ patch,
                             const float* __restrict__ lbl,
                             const float* __restrict__ pnorm,
                             const float* __restrict__ lnorm,
                             float* __restrict__ ctx) {
  const int lab = blockIdx.x;
  const int tid = threadIdx.x;
  __shared__ float lsh[CDIM];
  __shared__ float sv[64 * 8];
  __shared__ int   si[64 * 8];
  __shared__ int   cand[NCAND];
  __shared__ float ckey[NCAND];
  __shared__ int   nb[KTOP];

  lsh[tid] = lbl[(size_t)lab * CDIM + tid];
  const int total = NCH3 * KPS;  // 1008
  if (tid < 64) {
    float v[8]; int ii[8];
#pragma unroll
    for (int j = 0; j < 8; ++j) { v[j] = INFINITY; ii[j] = 0x7fffffff; }
    for (int e = tid; e < total; e += 64)
      tk_insert<8>(v, ii, part_s[(size_t)lab * total + e],
                   part_i[(size_t)lab * total + e]);
#pragma unroll
    for (int j = 0; j < 8; ++j) { sv[tid * 8 + j] = v[j]; si[tid * 8 + j] = ii[j]; }
  }
  __syncthreads();
  if (tid == 0) {
    float v[NCAND]; int ii[NCAND];
#pragma unroll
    for (int j = 0; j < NCAND; ++j) { v[j] = INFINITY; ii[j] = 0x7fffffff; }
    for (int e = 0; e < 64 * 8; ++e) tk_insert<NCAND>(v, ii, sv[e], si[e]);
#pragma unroll
    for (int j = 0; j < NCAND; ++j) cand[j] = ii[j];
  }
  __syncthreads();
  // exact np-f32 key per candidate: sequential fmaf chain k=0..255 (BLAS
  // order) + np_key expression tree — identical arithmetic to the R4 screen.
  if (tid < NCAND) {
    int c = cand[tid];
    float key = INFINITY;
    if (c != 0x7fffffff) {
      const float* prow = &patch[(size_t)c * CDIM];
      float dot = 0.f;
      for (int k = 0; k < CDIM; ++k) dot = fmaf(lsh[k], prow[k], dot);
      key = np_key(lnorm[lab], dot, pnorm[c]);
    }
    ckey[tid] = key;
  }
  __syncthreads();
  if (tid == 0) {
    unsigned long long used = 0;
    for (int t = 0; t < KTOP; ++t) {
      float best = INFINITY; int bj = 0, bidx = 0x7fffffff;
      for (int j = 0; j < NCAND; ++j) {
        if (used & (1ull << j)) continue;
        if (ckey[j] < best || (ckey[j] == best && cand[j] < bidx)) {
          best = ckey[j]; bj = j; bidx = cand[j];
        }
      }
      used |= (1ull << bj);
      nb[t] = cand[bj];
    }
  }
  __syncthreads();
  float mx = -INFINITY;
#pragma unroll
  for (int j = 0; j < KTOP; ++j)
    mx = fmaxf(mx, patch[(size_t)nb[j] * CDIM + tid]);
  ctx[(size_t)lab * CDIM + tid] = mx - lsh[tid];
}

// ---------------- FALLBACK: R4 f32 screen + merge (known-green) -------------

__global__ void k_screen_f32(const float* __restrict__ lbl,
                             const float* __restrict__ patch,
                             const float* __restrict__ pnorm,
                             const float* __restrict__ lnorm,
                             float* __restrict__ part_s,
                             int* __restrict__ part_i) {
  __shared__ float Asm[KC][BLK];
  __shared__ float Bsm[KC][BLK];
  __shared__ float sc[BLK][BLK + 1];
  const int tid = threadIdx.x;
  const int tr = tid >> 4, tc = tid & 15;
  const int lbase = blockIdx.y * BLK;
  const int chunk = blockIdx.x;
  const int p0 = chunk * CHUNK;
  const int p1 = (p0 + CHUNK < NPATCH) ? p0 + CHUNK : NPATCH;

  float tv[KP]; int ti[KP];
#pragma unroll
  for (int j = 0; j < KP; ++j) { tv[j] = INFINITY; ti[j] = 0x7fffffff; }
  const float ln = (tid < BLK) ? lnorm[lbase + tid] : 0.f;

  const int sl = tid >> 2;
  const int skq = (tid & 3) * 4;

  for (int pt = p0; pt < p1; pt += BLK) {
    float acc[4][4];
#pragma unroll
    for (int a = 0; a < 4; ++a)
#pragma unroll
      for (int b = 0; b < 4; ++b) acc[a][b] = 0.f;

    for (int kc = 0; kc < CDIM; kc += KC) {
      __syncthreads();
      {
        const float* arow = &lbl[(size_t)(lbase + sl) * CDIM + kc];
        float4 va0 = *(const float4*)(arow + skq);
        float4 va1 = *(const float4*)(arow + 16 + skq);
        Asm[skq + 0][sl] = va0.x; Asm[skq + 1][sl] = va0.y;
        Asm[skq + 2][sl] = va0.z; Asm[skq + 3][sl] = va0.w;
        Asm[16 + skq + 0][sl] = va1.x; Asm[16 + skq + 1][sl] = va1.y;
        Asm[16 + skq + 2][sl] = va1.z; Asm[16 + skq + 3][sl] = va1.w;
        int p = pt + sl;
        float4 vb0 = make_float4(0.f, 0.f, 0.f, 0.f), vb1 = vb0;
        if (p < p1) {
          const float* brow = &patch[(size_t)p * CDIM + kc];
          vb0 = *(const float4*)(brow + skq);
          vb1 = *(const float4*)(brow + 16 + skq);
        }
        Bsm[skq + 0][sl] = vb0.x; Bsm[skq + 1][sl] = vb0.y;
        Bsm[skq + 2][sl] = vb0.z; Bsm[skq + 3][sl] = vb0.w;
        Bsm[16 + skq + 0][sl] = vb1.x; Bsm[16 + skq + 1][sl] = vb1.y;
        Bsm[16 + skq + 2][sl] = vb1.z; Bsm[16 + skq + 3][sl] = vb1.w;
      }
      __syncthreads();
#pragma unroll
      for (int k = 0; k < KC; ++k) {
        float4 a4 = *(const float4*)&Asm[k][tr * 4];
        float4 b4 = *(const float4*)&Bsm[k][tc * 4];
        const float av[4] = {a4.x, a4.y, a4.z, a4.w};
        const float bv[4] = {b4.x, b4.y, b4.z, b4.w};
#pragma unroll
        for (int a = 0; a < 4; ++a)
#pragma unroll
          for (int b = 0; b < 4; ++b) acc[a][b] = fmaf(av[a], bv[b], acc[a][b]);
      }
    }
#pragma unroll
    for (int a = 0; a < 4; ++a)
#pragma unroll
      for (int b = 0; b < 4; ++b) sc[tr * 4 + a][tc * 4 + b] = acc[a][b];
    __syncthreads();
    if (tid < BLK) {
      for (int c = 0; c < BLK; ++c) {
        int p = pt + c;
        if (p < p1) tk_insert<KP>(tv, ti, np_key(ln, sc[tid][c], pnorm[p]), p);
      }
    }
  }

  if (tid < BLK) {
    int lab = lbase + tid;
    size_t base = ((size_t)lab * NCHUNK + chunk) * KP;
#pragma unroll
    for (int j = 0; j < KP; ++j) { part_s[base + j] = tv[j]; part_i[base + j] = ti[j]; }
  }
}

__global__ void k_merge_f32(const float* __restrict__ part_s,
                            const int* __restrict__ part_i,
                            const float* __restrict__ patch,
                            const float* __restrict__ lbl,
                            float* __restrict__ ctx) {
  const int lab = blockIdx.x;
  const int tid = threadIdx.x;
  __shared__ float cv[16][KP];
  __shared__ int ci[16][KP];
  __shared__ int nb[KTOP];

  const int total = NCHUNK * KP;
  if (tid < 16) {
    float v[KP]; int ii[KP];
#pragma unroll
    for (int j = 0; j < KP; ++j) { v[j] = INFINITY; ii[j] = 0x7fffffff; }
    for (int e = tid; e < total; e += 16)
      tk_insert<KP>(v, ii, part_s[(size_t)lab * total + e],
                    part_i[(size_t)lab * total + e]);
#pragma unroll
    for (int j = 0; j < KP; ++j) { cv[tid][j] = v[j]; ci[tid][j] = ii[j]; }
  }
  __syncthreads();
  if (tid == 0) {
    float v[KP]; int ii[KP];
#pragma unroll
    for (int j = 0; j < KP; ++j) { v[j] = INFINITY; ii[j] = 0x7fffffff; }
    for (int t = 0; t < 16; ++t)
      for (int j = 0; j < KP; ++j) tk_insert<KP>(v, ii, cv[t][j], ci[t][j]);
#pragma unroll
    for (int j = 0; j < KTOP; ++j) nb[j] = ii[j];
  }
  __syncthreads();
  float l = lbl[(size_t)lab * CDIM + tid];
  float mx = -INFINITY;
#pragma unroll
  for (int j = 0; j < KTOP; ++j)
    mx = fmaxf(mx, patch[(size_t)nb[j] * CDIM + tid]);
  ctx[(size_t)lab * CDIM + tid] = mx - l;
}

// ---------------- kernel: small label->label agg (np-f32 semantics) ---------

__global__ void k_small_agg(const float* __restrict__ lbl_rows,
                            const float* __restrict__ tgt, int M, int k,
                            float* __restrict__ ctx) {
  const int row = blockIdx.x;
  const int tid = threadIdx.x;
  __shared__ float lsh[CDIM];
  __shared__ float skey[256];
  __shared__ float lns;
  __shared__ int nb[4];
  lsh[tid] = lbl_rows[(size_t)row * CDIM + tid];
  __syncthreads();
  if (tid == 0) lns = np_sq256(lsh);
  __syncthreads();
  float key = INFINITY;
  if (tid < M) {
    const float* trow = &tgt[(size_t)tid * CDIM];
    float tn = np_sq256(trow);
    float dot = 0.f;
    for (int c = 0; c < CDIM; ++c) dot = fmaf(lsh[c], trow[c], dot);
    key = np_key(lns, dot, tn);
  }
  skey[tid] = key;
  __syncthreads();
  if (tid == 0) {
    for (int t = 0; t < k; ++t) {
      float best = INFINITY; int bi = 0;
      for (int j = 0; j < M; ++j)
        if (skey[j] < best) { best = skey[j]; bi = j; }
      nb[t] = bi; skey[bi] = INFINITY;
    }
  }
  __syncthreads();
  float mx = -INFINITY;
  for (int t = 0; t < k; ++t) mx = fmaxf(mx, tgt[(size_t)nb[t] * CDIM + tid]);
  ctx[(size_t)row * CDIM + tid] = mx - lsh[tid];
}

// ---------------- kernel: linear(concat) + residual + LayerNorm (f64) -------

__device__ __forceinline__ double block_sum_256d(double x, double* red) {
#pragma unroll
  for (int m = 32; m >= 1; m >>= 1) x += __shfl_xor(x, m);
  int wid = threadIdx.x >> 6, lane = threadIdx.x & 63;
  if (lane == 0) red[wid] = x;
  __syncthreads();
  double s = red[0] + red[1] + red[2] + red[3];
  __syncthreads();
  return s;
}

__global__ void k_level_out(const float* __restrict__ emb,
                            const float* __restrict__ c1,
                            const float* __restrict__ c2,
                            const float* __restrict__ c3, int nseg,
                            const float* __restrict__ W,
                            const float* __restrict__ bias,
                            const float* __restrict__ gamma,
                            const float* __restrict__ beta,
                            float* __restrict__ out) {
  __shared__ float xs[4 * CDIM];
  __shared__ double red[4];
  const int row = blockIdx.x, ch = threadIdx.x;
  float e = emb[(size_t)row * CDIM + ch];
  xs[ch] = e;
  if (nseg > 1) xs[CDIM + ch] = c1[(size_t)row * CDIM + ch];
  if (nseg > 2) xs[2 * CDIM + ch] = c2[(size_t)row * CDIM + ch];
  if (nseg > 3) xs[3 * CDIM + ch] = c3[(size_t)row * CDIM + ch];
  __syncthreads();
  const int F = nseg * CDIM;
  double y = (double)e + (double)bias[ch];
#pragma unroll 4
  for (int j = 0; j < F; ++j)
    y += (double)xs[j] * (double)W[(size_t)j * CDIM + ch];
  double mu = block_sum_256d(y, red) * (1.0 / 256.0);
  double d = y - mu;
  double var = block_sum_256d(d * d, red) * (1.0 / 256.0);
  out[(size_t)row * CDIM + ch] =
      (float)(d / sqrt(var + 1e-5) * (double)gamma[ch] + (double)beta[ch]);
}

// ---------------- launch ----------------------------------------------------

static void launch_tail(const float* mood_emb, const float* genre_emb,
                        const float* sub_emb, const float* Wm_w, const float* Wm_b,
                        const float* Wg_w, const float* Wg_b, const float* Ws_w,
                        const float* Ws_b, const float* lnm_g, const float* lnm_b,
                        const float* lng_g, const float* lng_b, const float* lns_g,
                        const float* lns_b, const float* ctx_all, float* ctx_gm,
                        float* ctx_sm, float* ctx_sg, float* out,
                        hipStream_t stream) {
  k_level_out<<<NMOOD, 256, 0, stream>>>(mood_emb, ctx_all, nullptr, nullptr, 2,
                                         Wm_w, Wm_b, lnm_g, lnm_b, out);
  k_small_agg<<<NGENRE, 256, 0, stream>>>(genre_emb, out, NMOOD, 4, ctx_gm);
  k_level_out<<<NGENRE, 256, 0, stream>>>(genre_emb, ctx_all + NMOOD * CDIM, ctx_gm,
                                          nullptr, 3, Wg_w, Wg_b, lng_g, lng_b,
                                          out + NMOOD * CDIM);
  k_small_agg<<<NSUB, 256, 0, stream>>>(sub_emb, out, NMOOD, 3, ctx_sm);
  k_small_agg<<<NSUB, 256, 0, stream>>>(sub_emb, out + NMOOD * CDIM, NGENRE, 4, ctx_sg);
  k_level_out<<<NSUB, 256, 0, stream>>>(sub_emb, ctx_all + (NMOOD + NGENRE) * CDIM,
                                        ctx_sm, ctx_sg, 4, Ws_w, Ws_b, lns_g, lns_b,
                                        out + NMOOD * CDIM + NGENRE * CDIM);
}

extern "C" void kernel_launch(void* const* d_in, const int* in_sizes, int n_in,
                              void* d_out, int out_size, void* d_ws, size_t ws_size,
                              hipStream_t stream) {
  const float* patch     = (const float*)d_in[0];
  const float* mood_emb  = (const float*)d_in[1];
  const float* genre_emb = (const float*)d_in[2];
  const float* sub_emb   = (const float*)d_in[3];
  const float* Wm_w = (const float*)d_in[4];
  const float* Wm_b = (const float*)d_in[5];
  const float* Wg_w = (const float*)d_in[6];
  const float* Wg_b = (const float*)d_in[7];
  const float* Ws_w = (const float*)d_in[8];
  const float* Ws_b = (const float*)d_in[9];
  const float* lnm_g = (const float*)d_in[10];
  const float* lnm_b = (const float*)d_in[11];
  const float* lng_g = (const float*)d_in[12];
  const float* lng_b = (const float*)d_in[13];
  const float* lns_g = (const float*)d_in[14];
  const float* lns_b = (const float*)d_in[15];
  float* out = (float*)d_out;
  float* ws = (float*)d_ws;

  const size_t REQ = 15438848ull * 4ull;  // ~61.8 MB

  if (ws_size >= REQ) {
    // ---- MFMA path layout ----
    float* lbl     = ws;                     // 212992
    float* pnorm   = lbl + NLBL * CDIM;      // 100352
    float* lnorm   = pnorm + 100352;         // 1024
    float* ctx_all = lnorm + 1024;           // 212992
    float* ctx_gm  = ctx_all + NLBL * CDIM;  // 65536
    float* ctx_sm  = ctx_gm + NGENRE * CDIM; // 131072
    float* ctx_sg  = ctx_sm + NSUB * CDIM;   // 131072
    float* part_s  = ctx_sg + NSUB * CDIM;   // 838656
    int*   part_i  = (int*)(part_s + (size_t)NLBL * NCH3 * KPS);
    unsigned short* patchbf = (unsigned short*)(part_i + (size_t)NLBL * NCH3 * KPS);
    unsigned short* lblbf   = patchbf + (size_t)NPATCH * CDIM;

    k_concat_labels<<<NLBL, 256, 0, stream>>>(mood_emb, genre_emb, sub_emb, lbl);
    k_norms_wave<<<512, 256, 0, stream>>>(patch, NPATCH, pnorm);
    k_norms_wave<<<16, 256, 0, stream>>>(lbl, NLBL, lnorm);
    k_tobf16<<<2048, 256, 0, stream>>>(patch, (size_t)NPATCH * CDIM / 8, patchbf);
    k_tobf16<<<128, 256, 0, stream>>>(lbl, (size_t)NLBL * CDIM / 8, lblbf);
    dim3 gscr(NLBL / 64, NCH3);
    k_screen_mfma<<<gscr, 256, 0, stream>>>(lblbf, patchbf, pnorm, part_s, part_i);
    k_merge_mfma<<<NLBL, 256, 0, stream>>>(part_s, part_i, patch, lbl, pnorm,
                                           lnorm, ctx_all);
    launch_tail(mood_emb, genre_emb, sub_emb, Wm_w, Wm_b, Wg_w, Wg_b, Ws_w, Ws_b,
                lnm_g, lnm_b, lng_g, lng_b, lns_g, lns_b, ctx_all, ctx_gm, ctx_sm,
                ctx_sg, out, stream);
  } else {
    // ---- R4 fallback layout (known to fit) ----
    float* lbl    = ws;
    float* pnorm  = lbl + NLBL * CDIM;
    float* lnorm  = pnorm + 100352;
    float* part_s = lnorm + 1024;
    int*   part_i = (int*)(part_s + NLBL * NCHUNK * KP);
    float* ctx_all = part_s + 2 * NLBL * NCHUNK * KP;
    float* ctx_gm  = ctx_all + NLBL * CDIM;
    float* ctx_sm  = ctx_gm + NGENRE * CDIM;
    float* ctx_sg  = ctx_sm + NSUB * CDIM;

    k_concat_labels<<<NLBL, 256, 0, stream>>>(mood_emb, genre_emb, sub_emb, lbl);
    k_norms_wave<<<512, 256, 0, stream>>>(patch, NPATCH, pnorm);
    k_norms_wave<<<16, 256, 0, stream>>>(lbl, NLBL, lnorm);
    dim3 gscr(NCHUNK, NLBL / BLK);
    k_screen_f32<<<gscr, 256, 0, stream>>>(lbl, patch, pnorm, lnorm, part_s, part_i);
    k_merge_f32<<<NLBL, 256, 0, stream>>>(part_s, part_i, patch, lbl, ctx_all);
    launch_tail(mood_emb, genre_emb, sub_emb, Wm_w, Wm_b, Wg_w, Wg_b, Ws_w, Ws_b,
                lnm_g, lnm_b, lng_g, lng_b, lns_g, lns_b, ctx_all, ctx_gm, ctx_sm,
                ctx_sg, out, stream);
  }
}

// Round 6
// 1405.335 us; speedup vs baseline: 1.6081x; 1.6081x over previous
//
#include <hip/hip_runtime.h>
#include <math.h>

#define NPATCH 100000
#define CDIM   256
#define NMOOD  64
#define NGENRE 256
#define NSUB   512
#define NLBL   832          // 64+256+512
#define KTOP   9

// ---- f32 fallback screen constants (R4, known-green) ----
#define NCHUNK 39
#define CHUNK  2624
#define BLK    64
#define KC     32
#define KP     12

// ---- MFMA screen constants ----
#define PBLK   1600         // patches per chunk (100 groups of 16 -> proven list stats)
#define NCH3   63           // 63*1600 = 100800 >= 100000
#define TILE   64           // patches per LDS tile
#define NTILE  (PBLK / TILE) // 25
#define KPS    16           // per-(label,chunk) partial size
#define SL     6            // per-lane list depth
#define NCAND  32           // exact re-rank candidate count

typedef __attribute__((ext_vector_type(8))) short bf16x8;
typedef __attribute__((ext_vector_type(8))) unsigned short u16x8;
typedef __attribute__((ext_vector_type(4))) float f32x4;

// ---------------- serial top-k insert (ascending by (val,idx)) --------------

template <int K>
__device__ __forceinline__ void tk_insert(float (&v)[K], int (&ii)[K],
                                          float s, int idx) {
  if (s < v[K - 1] || (s == v[K - 1] && idx < ii[K - 1])) {
    v[K - 1] = s; ii[K - 1] = idx;
#pragma unroll
    for (int t = K - 1; t > 0; --t) {
      bool sw = (v[t] < v[t - 1]) || (v[t] == v[t - 1] && ii[t] < ii[t - 1]);
      if (sw) {
        float fv = v[t]; v[t] = v[t - 1]; v[t - 1] = fv;
        int fi = ii[t]; ii[t] = ii[t - 1]; ii[t - 1] = fi;
      }
    }
  }
}

// ------ numpy-pairwise sum of squares over 256 contiguous floats ------------

__device__ float np_sq256(const float* a) {
  float b0, b1;
  {
    float r[8];
#pragma unroll
    for (int i = 0; i < 8; ++i) { float x = a[i]; r[i] = __fmul_rn(x, x); }
    for (int j = 8; j < 128; j += 8)
#pragma unroll
      for (int i = 0; i < 8; ++i) {
        float x = a[j + i];
        r[i] = __fadd_rn(r[i], __fmul_rn(x, x));
      }
    b0 = __fadd_rn(__fadd_rn(__fadd_rn(r[0], r[1]), __fadd_rn(r[2], r[3])),
                   __fadd_rn(__fadd_rn(r[4], r[5]), __fadd_rn(r[6], r[7])));
  }
  {
    float r[8];
#pragma unroll
    for (int i = 0; i < 8; ++i) { float x = a[128 + i]; r[i] = __fmul_rn(x, x); }
    for (int j = 8; j < 128; j += 8)
#pragma unroll
      for (int i = 0; i < 8; ++i) {
        float x = a[128 + j + i];
        r[i] = __fadd_rn(r[i], __fmul_rn(x, x));
      }
    b1 = __fadd_rn(__fadd_rn(__fadd_rn(r[0], r[1]), __fadd_rn(r[2], r[3])),
                   __fadd_rn(__fadd_rn(r[4], r[5]), __fadd_rn(r[6], r[7])));
  }
  return __fadd_rn(b0, b1);
}

__device__ __forceinline__ float np_key(float ln, float dot, float pn) {
  return __fadd_rn(__fsub_rn(ln, __fmul_rn(2.f, dot)), pn);
}

// ---------------- kernel: concat labels into one (832,256) matrix -----------

__global__ void k_concat_labels(const float* __restrict__ mood,
                                const float* __restrict__ genre,
                                const float* __restrict__ sub,
                                float* __restrict__ lbl) {
  int i = blockIdx.x * 256 + threadIdx.x;
  if (i < NMOOD * CDIM) lbl[i] = mood[i];
  else if (i < (NMOOD + NGENRE) * CDIM) lbl[i] = genre[i - NMOOD * CDIM];
  else lbl[i] = sub[i - (NMOOD + NGENRE) * CDIM];
}

// ---------------- kernel: wave-parallel numpy-pairwise row norms ------------

__global__ void k_norms_wave(const float* __restrict__ m, int n,
                             float* __restrict__ out) {
  int gw = (blockIdx.x * blockDim.x + threadIdx.x) >> 6;
  int lane = threadIdx.x & 63;
  int rsub = lane >> 3, i = lane & 7;
  int nw = (gridDim.x * blockDim.x) >> 6;
  for (int row0 = gw * 8; row0 < n; row0 += nw * 8) {
    int row = row0 + rsub;
    const float* a = m + (size_t)row * CDIM;
    float b[2];
#pragma unroll
    for (int blk = 0; blk < 2; ++blk) {
      const float* ab = a + blk * 128;
      float x = ab[i];
      float r = __fmul_rn(x, x);
      for (int j = 1; j < 16; ++j) {
        float y = ab[j * 8 + i];
        r = __fadd_rn(r, __fmul_rn(y, y));
      }
      float t = __fadd_rn(r, __shfl_xor(r, 1));
      t = __fadd_rn(t, __shfl_xor(t, 2));
      t = __fadd_rn(t, __shfl_xor(t, 4));
      b[blk] = t;
    }
    if (i == 0) out[row] = __fadd_rn(b[0], b[1]);
  }
}

// ---------------- kernel: f32 -> bf16 (RNE) conversion ----------------------

__device__ __forceinline__ unsigned short f2bf(float x) {
  unsigned u = __float_as_uint(x);
  return (unsigned short)((u + 0x7fffu + ((u >> 16) & 1u)) >> 16);
}

__global__ void k_tobf16(const float* __restrict__ src, size_t n8,
                         unsigned short* __restrict__ dst) {
  size_t i = (size_t)blockIdx.x * blockDim.x + threadIdx.x;
  size_t stride = (size_t)gridDim.x * blockDim.x;
  for (; i < n8; i += stride) {
    const float4* s = (const float4*)(src + i * 8);
    float4 x = s[0], y = s[1];
    u16x8 o;
    o[0] = f2bf(x.x); o[1] = f2bf(x.y); o[2] = f2bf(x.z); o[3] = f2bf(x.w);
    o[4] = f2bf(y.x); o[5] = f2bf(y.y); o[6] = f2bf(y.z); o[7] = f2bf(y.w);
    *(u16x8*)(dst + i * 8) = o;
  }
}

// ---------------- async global->LDS helper ----------------------------------

__device__ __forceinline__ void gload_lds16(const void* g, void* l) {
  __builtin_amdgcn_global_load_lds(
      (const __attribute__((address_space(1))) unsigned int*)g,
      (__attribute__((address_space(3))) unsigned int*)l, 16, 0, 0);
}

// ---------------- kernel: MFMA bf16 screen (LDS-staged, double-buffered) ----
// grid (13 label-groups, 63 chunks); block 256 = 4 waves, wave owns 16 labels
// (A-frags in registers). Patch tiles (64 rows x 512B) staged via
// global_load_lds with pre-swizzled SOURCE addresses (chunk ^ (row&7)) so the
// linear DMA write produces a bank-uniform layout; ds_read applies the same
// XOR (involution). Double-buffered with counted vmcnt(8) — never drained to
// 0 in the main loop. Keys approximate (bf16); exact re-rank downstream.

__global__ __launch_bounds__(256, 2) void k_screen_mfma(
    const unsigned short* __restrict__ lblbf,
    const unsigned short* __restrict__ patchbf,
    const float* __restrict__ pnorm,
    float* __restrict__ part_s, int* __restrict__ part_i) {
  __shared__ __align__(16) char smem[2][TILE * 512];  // 64 KB
  const int tid = threadIdx.x;
  const int w = tid >> 6, l = tid & 63;
  const int col = l & 15, kg = l >> 4;
  const int lgrp = blockIdx.x;
  const int chunk = blockIdx.y;
  const int lab0 = lgrp * 64 + w * 16;
  const int p0 = chunk * PBLK;

  bf16x8 a[8];
#pragma unroll
  for (int kk = 0; kk < 8; ++kk)
    a[kk] = *(const bf16x8*)&lblbf[(size_t)(lab0 + col) * CDIM + kk * 32 + kg * 8];

  float lv[4][SL]; int li[4][SL];
#pragma unroll
  for (int r = 0; r < 4; ++r)
#pragma unroll
    for (int j = 0; j < SL; ++j) { lv[r][j] = INFINITY; li[r][j] = 0x7fffffff; }

  auto stage = [&](int buf, int t) {
    int tp0 = p0 + t * TILE;
#pragma unroll
    for (int q = 0; q < 8; ++q) {
      int ci = q * 256 + tid;          // 16B chunk index in tile (0..2047)
      int row = ci >> 5, c = ci & 31;  // tile row, within-row 16B chunk
      int pr = tp0 + row;
      if (pr > NPATCH - 1) pr = NPATCH - 1;
      const void* g = (const void*)(patchbf + (size_t)pr * CDIM +
                                    ((c ^ (row & 7)) << 3));
      gload_lds16(g, &smem[buf][ci * 16]);
    }
  };

  stage(0, 0);
  for (int t = 0; t < NTILE; ++t) {
    const int cb = t & 1;
    if (t + 1 < NTILE) {
      stage(cb ^ 1, t + 1);
      asm volatile("s_waitcnt vmcnt(8)" ::: "memory");
    } else {
      asm volatile("s_waitcnt vmcnt(0)" ::: "memory");
    }
    __syncthreads();
    const char* cur = smem[cb];
    const int tp0 = p0 + t * TILE;
#pragma unroll
    for (int gg = 0; gg < 4; ++gg) {
      const int lrow = gg * 16 + col;
      const int xr = lrow & 7;
      const char* rb = cur + lrow * 512;
      bf16x8 b[8];
#pragma unroll
      for (int kk = 0; kk < 8; ++kk)
        b[kk] = *(const bf16x8*)(rb + (((kg + 4 * kk) ^ xr) << 4));
      f32x4 acc = {0.f, 0.f, 0.f, 0.f};
#pragma unroll
      for (int kk = 0; kk < 8; ++kk)
        acc = __builtin_amdgcn_mfma_f32_16x16x32_bf16(a[kk], b[kk], acc, 0, 0, 0);
      int p = tp0 + gg * 16 + col;
      bool ok = p < NPATCH;
      float pn = pnorm[ok ? p : NPATCH - 1];
      int pi = ok ? p : 0x7fffffff;
#pragma unroll
      for (int r = 0; r < 4; ++r) {
        float key = ok ? fmaf(-2.f, acc[r], pn) : INFINITY;
        tk_insert<SL>(lv[r], li[r], key, pi);
      }
    }
    __syncthreads();
  }

  // block-end merge: reuse the LDS buffers (main loop done)
  float (*stv)[16][SL] = (float (*)[16][SL])&smem[0][0];
  int (*sti)[16][SL]   = (int (*)[16][SL])&smem[0][24576];
#pragma unroll
  for (int r = 0; r < 4; ++r) {
    int s = w * 16 + kg * 4 + r;
#pragma unroll
    for (int j = 0; j < SL; ++j) { stv[s][col][j] = lv[r][j]; sti[s][col][j] = li[r][j]; }
  }
  __syncthreads();
  if (tid < 64) {
    float v[KPS]; int ii[KPS];
#pragma unroll
    for (int j = 0; j < KPS; ++j) { v[j] = INFINITY; ii[j] = 0x7fffffff; }
    for (int src = 0; src < 16; ++src)
#pragma unroll
      for (int j = 0; j < SL; ++j)
        tk_insert<KPS>(v, ii, stv[tid][src][j], sti[tid][src][j]);
    size_t base = ((size_t)(lgrp * 64 + tid) * NCH3 + chunk) * KPS;
#pragma unroll
    for (int j = 0; j < KPS; ++j) { part_s[base + j] = v[j]; part_i[base + j] = ii[j]; }
  }
}

// ---------------- kernel: merge + EXACT np-f32 re-rank + max-agg ------------
// tournament depths (12,16,32) all >= 9: a true top-9 entry has <= 8 smaller
// entries globally, so it can never be dropped at any stage.

__global__ void k_merge_mfma(const float* __restrict__ part_s,
                             const int* __restrict__ part_i,
                             const float* __restrict__ patch,
                             const float* __restrict__ lbl,
                             const float* __restrict__ pnorm,
                             const float* __restrict__ lnorm,
                             float* __restrict__ ctx) {
  const int lab = blockIdx.x;
  const int tid = threadIdx.x;
  __shared__ float lsh[CDIM];
  __shared__ float sv[64 * 12];
  __shared__ int   si[64 * 12];
  __shared__ float mv[8][16];
  __shared__ int   mi[8][16];
  __shared__ int   cand[NCAND];
  __shared__ float ckey[NCAND];
  __shared__ int   nb[KTOP];

  lsh[tid] = lbl[(size_t)lab * CDIM + tid];
  const int total = NCH3 * KPS;  // 1008
  if (tid < 64) {
    float v[12]; int ii[12];
#pragma unroll
    for (int j = 0; j < 12; ++j) { v[j] = INFINITY; ii[j] = 0x7fffffff; }
    for (int e = tid; e < total; e += 64)
      tk_insert<12>(v, ii, part_s[(size_t)lab * total + e],
                    part_i[(size_t)lab * total + e]);
#pragma unroll
    for (int j = 0; j < 12; ++j) { sv[tid * 12 + j] = v[j]; si[tid * 12 + j] = ii[j]; }
  }
  __syncthreads();
  if (tid < 8) {
    float v[16]; int ii[16];
#pragma unroll
    for (int j = 0; j < 16; ++j) { v[j] = INFINITY; ii[j] = 0x7fffffff; }
    for (int e = 0; e < 8 * 12; ++e)
      tk_insert<16>(v, ii, sv[tid * 96 + e], si[tid * 96 + e]);
#pragma unroll
    for (int j = 0; j < 16; ++j) { mv[tid][j] = v[j]; mi[tid][j] = ii[j]; }
  }
  __syncthreads();
  if (tid == 0) {
    float v[NCAND]; int ii[NCAND];
#pragma unroll
    for (int j = 0; j < NCAND; ++j) { v[j] = INFINITY; ii[j] = 0x7fffffff; }
    for (int e = 0; e < 128; ++e)
      tk_insert<NCAND>(v, ii, mv[e >> 4][e & 15], mi[e >> 4][e & 15]);
#pragma unroll
    for (int j = 0; j < NCAND; ++j) cand[j] = ii[j];
  }
  __syncthreads();
  // exact np-f32 key per candidate (sequential fmaf chain, BLAS order)
  if (tid < NCAND) {
    int c = cand[tid];
    float key = INFINITY;
    if (c != 0x7fffffff) {
      const float* prow = &patch[(size_t)c * CDIM];
      float dot = 0.f;
      for (int k = 0; k < CDIM; ++k) dot = fmaf(lsh[k], prow[k], dot);
      key = np_key(lnorm[lab], dot, pnorm[c]);
    }
    ckey[tid] = key;
  }
  __syncthreads();
  if (tid == 0) {
    unsigned long long used = 0;
    for (int t = 0; t < KTOP; ++t) {
      float best = INFINITY; int bj = 0, bidx = 0x7fffffff;
      for (int j = 0; j < NCAND; ++j) {
        if (used & (1ull << j)) continue;
        if (ckey[j] < best || (ckey[j] == best && cand[j] < bidx)) {
          best = ckey[j]; bj = j; bidx = cand[j];
        }
      }
      used |= (1ull << bj);
      nb[t] = cand[bj];
    }
  }
  __syncthreads();
  float mx = -INFINITY;
#pragma unroll
  for (int j = 0; j < KTOP; ++j)
    mx = fmaxf(mx, patch[(size_t)nb[j] * CDIM + tid]);
  ctx[(size_t)lab * CDIM + tid] = mx - lsh[tid];
}

// ---------------- FALLBACK: R4 f32 screen + merge (known-green) -------------

__global__ void k_screen_f32(const float* __restrict__ lbl,
                             const float* __restrict__ patch,
                             const float* __restrict__ pnorm,
                             const float* __restrict__ lnorm,
                             float* __restrict__ part_s,
                             int* __restrict__ part_i) {
  __shared__ float Asm[KC][BLK];
  __shared__ float Bsm[KC][BLK];
  __shared__ float sc[BLK][BLK + 1];
  const int tid = threadIdx.x;
  const int tr = tid >> 4, tc = tid & 15;
  const int lbase = blockIdx.y * BLK;
  const int chunk = blockIdx.x;
  const int p0 = chunk * CHUNK;
  const int p1 = (p0 + CHUNK < NPATCH) ? p0 + CHUNK : NPATCH;

  float tv[KP]; int ti[KP];
#pragma unroll
  for (int j = 0; j < KP; ++j) { tv[j] = INFINITY; ti[j] = 0x7fffffff; }
  const float ln = (tid < BLK) ? lnorm[lbase + tid] : 0.f;

  const int sl = tid >> 2;
  const int skq = (tid & 3) * 4;

  for (int pt = p0; pt < p1; pt += BLK) {
    float acc[4][4];
#pragma unroll
    for (int a = 0; a < 4; ++a)
#pragma unroll
      for (int b = 0; b < 4; ++b) acc[a][b] = 0.f;

    for (int kc = 0; kc < CDIM; kc += KC) {
      __syncthreads();
      {
        const float* arow = &lbl[(size_t)(lbase + sl) * CDIM + kc];
        float4 va0 = *(const float4*)(arow + skq);
        float4 va1 = *(const float4*)(arow + 16 + skq);
        Asm[skq + 0][sl] = va0.x; Asm[skq + 1][sl] = va0.y;
        Asm[skq + 2][sl] = va0.z; Asm[skq + 3][sl] = va0.w;
        Asm[16 + skq + 0][sl] = va1.x; Asm[16 + skq + 1][sl] = va1.y;
        Asm[16 + skq + 2][sl] = va1.z; Asm[16 + skq + 3][sl] = va1.w;
        int p = pt + sl;
        float4 vb0 = make_float4(0.f, 0.f, 0.f, 0.f), vb1 = vb0;
        if (p < p1) {
          const float* brow = &patch[(size_t)p * CDIM + kc];
          vb0 = *(const float4*)(brow + skq);
          vb1 = *(const float4*)(brow + 16 + skq);
        }
        Bsm[skq + 0][sl] = vb0.x; Bsm[skq + 1][sl] = vb0.y;
        Bsm[skq + 2][sl] = vb0.z; Bsm[skq + 3][sl] = vb0.w;
        Bsm[16 + skq + 0][sl] = vb1.x; Bsm[16 + skq + 1][sl] = vb1.y;
        Bsm[16 + skq + 2][sl] = vb1.z; Bsm[16 + skq + 3][sl] = vb1.w;
      }
      __syncthreads();
#pragma unroll
      for (int k = 0; k < KC; ++k) {
        float4 a4 = *(const float4*)&Asm[k][tr * 4];
        float4 b4 = *(const float4*)&Bsm[k][tc * 4];
        const float av[4] = {a4.x, a4.y, a4.z, a4.w};
        const float bv[4] = {b4.x, b4.y, b4.z, b4.w};
#pragma unroll
        for (int a = 0; a < 4; ++a)
#pragma unroll
          for (int b = 0; b < 4; ++b) acc[a][b] = fmaf(av[a], bv[b], acc[a][b]);
      }
    }
#pragma unroll
    for (int a = 0; a < 4; ++a)
#pragma unroll
      for (int b = 0; b < 4; ++b) sc[tr * 4 + a][tc * 4 + b] = acc[a][b];
    __syncthreads();
    if (tid < BLK) {
      for (int c = 0; c < BLK; ++c) {
        int p = pt + c;
        if (p < p1) tk_insert<KP>(tv, ti, np_key(ln, sc[tid][c], pnorm[p]), p);
      }
    }
  }

  if (tid < BLK) {
    int lab = lbase + tid;
    size_t base = ((size_t)lab * NCHUNK + chunk) * KP;
#pragma unroll
    for (int j = 0; j < KP; ++j) { part_s[base + j] = tv[j]; part_i[base + j] = ti[j]; }
  }
}

__global__ void k_merge_f32(const float* __restrict__ part_s,
                            const int* __restrict__ part_i,
                            const float* __restrict__ patch,
                            const float* __restrict__ lbl,
                            float* __restrict__ ctx) {
  const int lab = blockIdx.x;
  const int tid = threadIdx.x;
  __shared__ float cv[16][KP];
  __shared__ int ci[16][KP];
  __shared__ int nb[KTOP];

  const int total = NCHUNK * KP;
  if (tid < 16) {
    float v[KP]; int ii[KP];
#pragma unroll
    for (int j = 0; j < KP; ++j) { v[j] = INFINITY; ii[j] = 0x7fffffff; }
    for (int e = tid; e < total; e += 16)
      tk_insert<KP>(v, ii, part_s[(size_t)lab * total + e],
                    part_i[(size_t)lab * total + e]);
#pragma unroll
    for (int j = 0; j < KP; ++j) { cv[tid][j] = v[j]; ci[tid][j] = ii[j]; }
  }
  __syncthreads();
  if (tid == 0) {
    float v[KP]; int ii[KP];
#pragma unroll
    for (int j = 0; j < KP; ++j) { v[j] = INFINITY; ii[j] = 0x7fffffff; }
    for (int t = 0; t < 16; ++t)
      for (int j = 0; j < KP; ++j) tk_insert<KP>(v, ii, cv[t][j], ci[t][j]);
#pragma unroll
    for (int j = 0; j < KTOP; ++j) nb[j] = ii[j];
  }
  __syncthreads();
  float l = lbl[(size_t)lab * CDIM + tid];
  float mx = -INFINITY;
#pragma unroll
  for (int j = 0; j < KTOP; ++j)
    mx = fmaxf(mx, patch[(size_t)nb[j] * CDIM + tid]);
  ctx[(size_t)lab * CDIM + tid] = mx - l;
}

// ---------------- kernel: small label->label agg (np-f32 semantics) ---------

__global__ void k_small_agg(const float* __restrict__ lbl_rows,
                            const float* __restrict__ tgt, int M, int k,
                            float* __restrict__ ctx) {
  const int row = blockIdx.x;
  const int tid = threadIdx.x;
  __shared__ float lsh[CDIM];
  __shared__ float skey[256];
  __shared__ float lns;
  __shared__ int nb[4];
  lsh[tid] = lbl_rows[(size_t)row * CDIM + tid];
  __syncthreads();
  if (tid == 0) lns = np_sq256(lsh);
  __syncthreads();
  float key = INFINITY;
  if (tid < M) {
    const float* trow = &tgt[(size_t)tid * CDIM];
    float tn = np_sq256(trow);
    float dot = 0.f;
    for (int c = 0; c < CDIM; ++c) dot = fmaf(lsh[c], trow[c], dot);
    key = np_key(lns, dot, tn);
  }
  skey[tid] = key;
  __syncthreads();
  if (tid == 0) {
    for (int t = 0; t < k; ++t) {
      float best = INFINITY; int bi = 0;
      for (int j = 0; j < M; ++j)
        if (skey[j] < best) { best = skey[j]; bi = j; }
      nb[t] = bi; skey[bi] = INFINITY;
    }
  }
  __syncthreads();
  float mx = -INFINITY;
  for (int t = 0; t < k; ++t) mx = fmaxf(mx, tgt[(size_t)nb[t] * CDIM + tid]);
  ctx[(size_t)row * CDIM + tid] = mx - lsh[tid];
}

// ---------------- kernel: linear(concat) + residual + LayerNorm (f64) -------

__device__ __forceinline__ double block_sum_256d(double x, double* red) {
#pragma unroll
  for (int m = 32; m >= 1; m >>= 1) x += __shfl_xor(x, m);
  int wid = threadIdx.x >> 6, lane = threadIdx.x & 63;
  if (lane == 0) red[wid] = x;
  __syncthreads();
  double s = red[0] + red[1] + red[2] + red[3];
  __syncthreads();
  return s;
}

__global__ void k_level_out(const float* __restrict__ emb,
                            const float* __restrict__ c1,
                            const float* __restrict__ c2,
                            const float* __restrict__ c3, int nseg,
                            const float* __restrict__ W,
                            const float* __restrict__ bias,
                            const float* __restrict__ gamma,
                            const float* __restrict__ beta,
                            float* __restrict__ out) {
  __shared__ float xs[4 * CDIM];
  __shared__ double red[4];
  const int row = blockIdx.x, ch = threadIdx.x;
  float e = emb[(size_t)row * CDIM + ch];
  xs[ch] = e;
  if (nseg > 1) xs[CDIM + ch] = c1[(size_t)row * CDIM + ch];
  if (nseg > 2) xs[2 * CDIM + ch] = c2[(size_t)row * CDIM + ch];
  if (nseg > 3) xs[3 * CDIM + ch] = c3[(size_t)row * CDIM + ch];
  __syncthreads();
  const int F = nseg * CDIM;
  double y = (double)e + (double)bias[ch];
#pragma unroll 4
  for (int j = 0; j < F; ++j)
    y += (double)xs[j] * (double)W[(size_t)j * CDIM + ch];
  double mu = block_sum_256d(y, red) * (1.0 / 256.0);
  double d = y - mu;
  double var = block_sum_256d(d * d, red) * (1.0 / 256.0);
  out[(size_t)row * CDIM + ch] =
      (float)(d / sqrt(var + 1e-5) * (double)gamma[ch] + (double)beta[ch]);
}

// ---------------- launch ----------------------------------------------------

static void launch_tail(const float* mood_emb, const float* genre_emb,
                        const float* sub_emb, const float* Wm_w, const float* Wm_b,
                        const float* Wg_w, const float* Wg_b, const float* Ws_w,
                        const float* Ws_b, const float* lnm_g, const float* lnm_b,
                        const float* lng_g, const float* lng_b, const float* lns_g,
                        const float* lns_b, const float* ctx_all, float* ctx_gm,
                        float* ctx_sm, float* ctx_sg, float* out,
                        hipStream_t stream) {
  k_level_out<<<NMOOD, 256, 0, stream>>>(mood_emb, ctx_all, nullptr, nullptr, 2,
                                         Wm_w, Wm_b, lnm_g, lnm_b, out);
  k_small_agg<<<NGENRE, 256, 0, stream>>>(genre_emb, out, NMOOD, 4, ctx_gm);
  k_level_out<<<NGENRE, 256, 0, stream>>>(genre_emb, ctx_all + NMOOD * CDIM, ctx_gm,
                                          nullptr, 3, Wg_w, Wg_b, lng_g, lng_b,
                                          out + NMOOD * CDIM);
  k_small_agg<<<NSUB, 256, 0, stream>>>(sub_emb, out, NMOOD, 3, ctx_sm);
  k_small_agg<<<NSUB, 256, 0, stream>>>(sub_emb, out + NMOOD * CDIM, NGENRE, 4, ctx_sg);
  k_level_out<<<NSUB, 256, 0, stream>>>(sub_emb, ctx_all + (NMOOD + NGENRE) * CDIM,
                                        ctx_sm, ctx_sg, 4, Ws_w, Ws_b, lns_g, lns_b,
                                        out + NMOOD * CDIM + NGENRE * CDIM);
}

extern "C" void kernel_launch(void* const* d_in, const int* in_sizes, int n_in,
                              void* d_out, int out_size, void* d_ws, size_t ws_size,
                              hipStream_t stream) {
  const float* patch     = (const float*)d_in[0];
  const float* mood_emb  = (const float*)d_in[1];
  const float* genre_emb = (const float*)d_in[2];
  const float* sub_emb   = (const float*)d_in[3];
  const float* Wm_w = (const float*)d_in[4];
  const float* Wm_b = (const float*)d_in[5];
  const float* Wg_w = (const float*)d_in[6];
  const float* Wg_b = (const float*)d_in[7];
  const float* Ws_w = (const float*)d_in[8];
  const float* Ws_b = (const float*)d_in[9];
  const float* lnm_g = (const float*)d_in[10];
  const float* lnm_b = (const float*)d_in[11];
  const float* lng_g = (const float*)d_in[12];
  const float* lng_b = (const float*)d_in[13];
  const float* lns_g = (const float*)d_in[14];
  const float* lns_b = (const float*)d_in[15];
  float* out = (float*)d_out;
  float* ws = (float*)d_ws;

  const size_t REQ = 15438848ull * 4ull;  // ~61.8 MB

  if (ws_size >= REQ) {
    // ---- MFMA path layout ----
    float* lbl     = ws;                     // 212992
    float* pnorm   = lbl + NLBL * CDIM;      // 100352
    float* lnorm   = pnorm + 100352;         // 1024
    float* ctx_all = lnorm + 1024;           // 212992
    float* ctx_gm  = ctx_all + NLBL * CDIM;  // 65536
    float* ctx_sm  = ctx_gm + NGENRE * CDIM; // 131072
    float* ctx_sg  = ctx_sm + NSUB * CDIM;   // 131072
    float* part_s  = ctx_sg + NSUB * CDIM;   // 832*63*16 = 838656
    int*   part_i  = (int*)(part_s + (size_t)NLBL * NCH3 * KPS);
    unsigned short* patchbf = (unsigned short*)(part_i + (size_t)NLBL * NCH3 * KPS);
    unsigned short* lblbf   = patchbf + (size_t)NPATCH * CDIM;

    k_concat_labels<<<NLBL, 256, 0, stream>>>(mood_emb, genre_emb, sub_emb, lbl);
    k_norms_wave<<<512, 256, 0, stream>>>(patch, NPATCH, pnorm);
    k_norms_wave<<<16, 256, 0, stream>>>(lbl, NLBL, lnorm);
    k_tobf16<<<2048, 256, 0, stream>>>(patch, (size_t)NPATCH * CDIM / 8, patchbf);
    k_tobf16<<<128, 256, 0, stream>>>(lbl, (size_t)NLBL * CDIM / 8, lblbf);
    dim3 gscr(NLBL / 64, NCH3);
    k_screen_mfma<<<gscr, 256, 0, stream>>>(lblbf, patchbf, pnorm, part_s, part_i);
    k_merge_mfma<<<NLBL, 256, 0, stream>>>(part_s, part_i, patch, lbl, pnorm,
                                           lnorm, ctx_all);
    launch_tail(mood_emb, genre_emb, sub_emb, Wm_w, Wm_b, Wg_w, Wg_b, Ws_w, Ws_b,
                lnm_g, lnm_b, lng_g, lng_b, lns_g, lns_b, ctx_all, ctx_gm, ctx_sm,
                ctx_sg, out, stream);
  } else {
    // ---- R4 fallback layout (known to fit) ----
    float* lbl    = ws;
    float* pnorm  = lbl + NLBL * CDIM;
    float* lnorm  = pnorm + 100352;
    float* part_s = lnorm + 1024;
    int*   part_i = (int*)(part_s + NLBL * NCHUNK * KP);
    float* ctx_all = part_s + 2 * NLBL * NCHUNK * KP;
    float* ctx_gm  = ctx_all + NLBL * CDIM;
    float* ctx_sm  = ctx_gm + NGENRE * CDIM;
    float* ctx_sg  = ctx_sm + NSUB * CDIM;

    k_concat_labels<<<NLBL, 256, 0, stream>>>(mood_emb, genre_emb, sub_emb, lbl);
    k_norms_wave<<<512, 256, 0, stream>>>(patch, NPATCH, pnorm);
    k_norms_wave<<<16, 256, 0, stream>>>(lbl, NLBL, lnorm);
    dim3 gscr(NCHUNK, NLBL / BLK);
    k_screen_f32<<<gscr, 256, 0, stream>>>(lbl, patch, pnorm, lnorm, part_s, part_i);
    k_merge_f32<<<NLBL, 256, 0, stream>>>(part_s, part_i, patch, lbl, ctx_all);
    launch_tail(mood_emb, genre_emb, sub_emb, Wm_w, Wm_b, Wg_w, Wg_b, Ws_w, Ws_b,
                lnm_g, lnm_b, lng_g, lng_b, lns_g, lns_b, ctx_all, ctx_gm, ctx_sm,
                ctx_sg, out, stream);
  }
}